// Round 4
// baseline (243.895 us; speedup 1.0000x reference)
//
#include <hip/hip_runtime.h>
#include <cfloat>
#include <cmath>

#define MEM_DIM 2000
#define FEA     256
#define LAMBDA  0.0025f
#define HS_EPS  1e-12f

typedef unsigned short u16;
typedef _Float16 f16x8  __attribute__((ext_vector_type(8)));
typedef float    f32x16 __attribute__((ext_vector_type(16)));

static const int Y_ELEMS = 16 * 256 * 1024;   // y output elements

// workspace layout (float offsets): wsp u16[2][2048][256] = 2 MB at 0
#define WS_ZP 524288     // [16][16384] partial sum(e^z) per m-tile (1 MB)
// xs (f16 split of x, 16.8 MB) lives in the y output region (free until k_pv2).

// ---------------------------------------------------------------------------
// Kernel A: split x [16][256][1024] f32 -> xs planes [2][16][1024][256] f16
// (hw-major, c contiguous). Plane1 = f16(x), plane2 = f16((x-hi)*256)
// ---------------------------------------------------------------------------
__global__ __launch_bounds__(256) void k_split_x(const float* __restrict__ x,
                                                 u16* __restrict__ xs) {
    __shared__ float tl[32][33];
    const int blk = blockIdx.x;           // 4096 = 16 b * 8 ct * 32 ht
    const int b   = blk >> 8;
    const int ct  = (blk >> 5) & 7;
    const int ht  = blk & 31;
    const int tx  = threadIdx.x & 31, ty = threadIdx.x >> 5;
#pragma unroll
    for (int i = 0; i < 4; ++i)
        tl[ty + 8 * i][tx] =
            x[(((b << 8) + (ct << 5) + ty + (i << 3)) << 10) + (ht << 5) + tx];
    __syncthreads();
#pragma unroll
    for (int i = 0; i < 4; ++i) {
        float v = tl[tx][ty + 8 * i];
        _Float16 a  = (_Float16)v;
        _Float16 bq = (_Float16)((v - (float)a) * 256.0f);
        const int hw = (ht << 5) + ty + (i << 3);
        const int c  = (ct << 5) + tx;
        const size_t o = (((size_t)(b << 10) + hw) << 8) + c;
        xs[o]           = *(u16*)&a;
        xs[4194304 + o] = *(u16*)&bq;
    }
}

// ---------------------------------------------------------------------------
// Kernel B: split W [2000][256] f32 -> wsp [2][2048][256] f16 (m zero-padded)
// ---------------------------------------------------------------------------
__global__ __launch_bounds__(256) void k_split_w(const float* __restrict__ W,
                                                 u16* __restrict__ wsp) {
    const int m = blockIdx.x;             // 2048
    const int c = threadIdx.x;
    float v = (m < MEM_DIM) ? W[(m << 8) + c] : 0.f;
    _Float16 a  = (_Float16)v;
    _Float16 bq = (_Float16)((v - (float)a) * 256.0f);
    wsp[(m << 8) + c]          = *(u16*)&a;
    wsp[524288 + (m << 8) + c] = *(u16*)&bq;
}

// ---------------------------------------------------------------------------
// Kernel 1: z = x.W^T via mfma_f32_32x32x16_f16, 2-split (3 passes, dual acc).
// Block: 128 rows x 128 m, BK=32, 4 waves (2x2), wave tile 64x64.
// LDS 64 KB: DOUBLE-buffered 32 KB tiles {A0,A1,B0,B1}, each [128][32] f16.
// Chunk swizzle: phys chunk = logical chunk ^ ((row>>1)&3)  (2-way = free).
// 2-phase pipeline: STAGE(next) -> COMPUTE(cur) -> barrier (T3 minimum).
// Epilogue: E=exp(z) -> S (att region, [b][m][1024]), row partial sums -> zp.
// ---------------------------------------------------------------------------
__global__ __launch_bounds__(256) void k_scores_mfma(
    const u16* __restrict__ xs, const u16* __restrict__ wsp,
    float* __restrict__ S, float* __restrict__ zp) {
    __shared__ u16 lds[32768];   // 64 KB = 2 x 32 KB buffers
    const int t    = threadIdx.x;
    const int lane = t & 63;
    const int w    = t >> 6;
    const int wr   = w >> 1, wc = w & 1;
    const int lr   = lane & 31, lg = lane >> 5;

    const int bx  = blockIdx.x;
    const int wg  = ((bx & 7) << 8) | (bx >> 3);   // XCD swizzle (2048 = 8*256)
    const int m0t = wg & 15;
    const int rt  = wg >> 4;
    const int m0  = m0t << 7;
    const int b   = rt >> 3;
    const int hw0 = (rt & 7) << 7;

    // staging: 8 issues x 256 thr x 16 B = 32 KB/buffer. slot s -> tile(s>>9),
    // row r=(s&511)>>2, phys chunk cp=s&3 holds logical chunk cp^((r>>1)&3).
    const u16* gsrc[8];
#pragma unroll
    for (int i = 0; i < 8; ++i) {
        const int s = (i << 8) + t;
        const int tile = s >> 9;
        const int u = s & 511;
        const int r = u >> 2;
        const int cl = (u & 3) ^ ((r >> 1) & 3);
        if (tile < 2)
            gsrc[i] = xs + tile * 4194304 + (((b << 10) + hw0 + r) << 8) + (cl << 3);
        else
            gsrc[i] = wsp + ((tile - 2) << 19) + ((m0 + r) << 8) + (cl << 3);
    }

    f32x16 acc1[2][2], acc2[2][2];
#pragma unroll
    for (int i = 0; i < 2; ++i)
#pragma unroll
        for (int j = 0; j < 2; ++j)
#pragma unroll
            for (int e = 0; e < 16; ++e) { acc1[i][j][e] = 0.f; acc2[i][j][e] = 0.f; }

    #define STAGE(kt, bufb)                                                          \
        {                                                                            \
            _Pragma("unroll")                                                        \
            for (int i = 0; i < 8; ++i) {                                            \
                const int s = (i << 8) + t;                                          \
                __builtin_amdgcn_global_load_lds(                                    \
                    (const __attribute__((address_space(1))) unsigned int*)(gsrc[i] + ((kt) << 5)), \
                    (__attribute__((address_space(3))) unsigned int*)&lds[(bufb) + (s << 3)],       \
                    16, 0, 0);                                                       \
            }                                                                        \
        }

    #define COMPUTE(bufb)                                                            \
        {                                                                            \
            _Pragma("unroll")                                                        \
            for (int ks = 0; ks < 2; ++ks) {                                         \
                f16x8 a0[2], a1[2], b0[2], b1[2];                                    \
                _Pragma("unroll")                                                    \
                for (int ri = 0; ri < 2; ++ri) {                                     \
                    const int R  = (wr << 6) + (ri << 5) + lr;                       \
                    const int pc = ((ks << 1) + lg) ^ ((R >> 1) & 3);                \
                    a0[ri] = *(const f16x8*)&lds[(bufb) +        (R << 5) + (pc << 3)]; \
                    a1[ri] = *(const f16x8*)&lds[(bufb) + 4096 + (R << 5) + (pc << 3)]; \
                }                                                                    \
                _Pragma("unroll")                                                    \
                for (int mi = 0; mi < 2; ++mi) {                                     \
                    const int M  = (wc << 6) + (mi << 5) + lr;                       \
                    const int pc = ((ks << 1) + lg) ^ ((M >> 1) & 3);                \
                    b0[mi] = *(const f16x8*)&lds[(bufb) +  8192 + (M << 5) + (pc << 3)]; \
                    b1[mi] = *(const f16x8*)&lds[(bufb) + 12288 + (M << 5) + (pc << 3)]; \
                }                                                                    \
                _Pragma("unroll")                                                    \
                for (int ri = 0; ri < 2; ++ri)                                       \
                    _Pragma("unroll")                                                \
                    for (int mi = 0; mi < 2; ++mi) {                                 \
                        acc2[ri][mi] = __builtin_amdgcn_mfma_f32_32x32x16_f16(a0[ri], b1[mi], acc2[ri][mi], 0, 0, 0); \
                        acc2[ri][mi] = __builtin_amdgcn_mfma_f32_32x32x16_f16(a1[ri], b0[mi], acc2[ri][mi], 0, 0, 0); \
                        acc1[ri][mi] = __builtin_amdgcn_mfma_f32_32x32x16_f16(a0[ri], b0[mi], acc1[ri][mi], 0, 0, 0); \
                    }                                                                \
            }                                                                        \
        }

    // prologue: fill buffer 0 with K-tile 0
    STAGE(0, 0);
    __syncthreads();                 // drains vmcnt -> tile 0 ready
#pragma unroll
    for (int kt = 0; kt < 8; ++kt) {
        if (kt < 7) STAGE(kt + 1, ((kt + 1) & 1) << 14);   // prefetch next tile
        COMPUTE((kt & 1) << 14);                           // compute current
        __syncthreads();             // drain prefetch + all waves done reading
    }
    #undef STAGE
    #undef COMPUTE

    float* zf = (float*)lds;

    float rs[2][16];
#pragma unroll
    for (int ri = 0; ri < 2; ++ri)
#pragma unroll
        for (int q = 0; q < 16; ++q) rs[ri][q] = 0.f;

#pragma unroll
    for (int ri = 0; ri < 2; ++ri)
#pragma unroll
        for (int mi = 0; mi < 2; ++mi) {
            const int m = m0 + (wc << 6) + (mi << 5) + lr;
            const bool valid = (m < MEM_DIM);
            float e[16];
#pragma unroll
            for (int q = 0; q < 16; ++q) {
                float z = acc1[ri][mi][q] + acc2[ri][mi][q] * 0.00390625f;
                e[q] = valid ? expf(z) : 0.f;
                rs[ri][q] += e[q];
            }
            if (valid) {
                const size_t pb = ((size_t)(b * MEM_DIM + m) << 10) + hw0
                                + (wr << 6) + (ri << 5) + (lg << 2);
#pragma unroll
                for (int q4 = 0; q4 < 4; ++q4) {
                    float4 v = {e[4 * q4], e[4 * q4 + 1], e[4 * q4 + 2], e[4 * q4 + 3]};
                    *(float4*)&S[pb + (q4 << 3)] = v;
                }
            }
        }

#pragma unroll
    for (int ri = 0; ri < 2; ++ri)
#pragma unroll
        for (int q = 0; q < 16; ++q) {
            float v = rs[ri][q];
            v += __shfl_xor(v, 1);
            v += __shfl_xor(v, 2);
            v += __shfl_xor(v, 4);
            v += __shfl_xor(v, 8);
            v += __shfl_xor(v, 16);
            rs[ri][q] = v;
        }
    if (lr == 0) {
#pragma unroll
        for (int ri = 0; ri < 2; ++ri)
#pragma unroll
            for (int q = 0; q < 16; ++q) {
                const int row = (wr << 6) + (ri << 5) + (q & 3) + ((q >> 2) << 3) + (lg << 2);
                zf[(wc << 7) + row] = rs[ri][q];
            }
    }
    __syncthreads();
    if (t < 128)
        zp[m0t * 16384 + (b << 10) + hw0 + t] = zf[t] + zf[128 + t];
}

// ---------------------------------------------------------------------------
// Kernel 2: fused shrink + normalize + sparse PV.
// Block = 64 hw rows x full m range (8 waves). Pass A: read E, reduce D.
// Pass B: re-read E (L2-hot), recompute s bit-identically, write final
// att = s*rD everywhere (zeros included), ballot-accumulate y.
// ---------------------------------------------------------------------------
__global__ __launch_bounds__(512) void k_pv2(float* __restrict__ att,
                                             const float* __restrict__ W,
                                             float* __restrict__ y,
                                             const float* __restrict__ zp) {
    __shared__ float ylds[64][257];
    __shared__ float dred[8][64];
    const int t    = threadIdx.x;
    const int beta = blockIdx.x;
    const int b    = beta >> 4;
    const int hw0  = (beta & 15) << 6;
    const int lane = t & 63, wv = t >> 6;
    const int row  = b * 1024 + hw0 + lane;

    for (int i = t; i < 64 * 257; i += 512) ((float*)ylds)[i] = 0.f;

    // full-row Z from the 16 m-tile partials
    float Z = 0.f;
#pragma unroll
    for (int mt = 0; mt < 16; ++mt) Z += zp[mt * 16384 + row];
    const float rZ = 1.f / Z;

    const size_t base = ((size_t)(b * MEM_DIM) << 10) + hw0 + lane;

    // ---- pass A: L1 denom D = sum_m s(m) ----
    float D = 0.f;
    for (int m = wv; m < MEM_DIM; m += 8) {
        float e = att[base + ((size_t)m << 10)];
        float a = e * rZ;
        float d = a - LAMBDA;
        D += fmaxf(d, 0.f) * a / (fabsf(d) + HS_EPS);
    }
    dred[wv][lane] = D;
    __syncthreads();
    float Dv = 0.f;
#pragma unroll
    for (int ww = 0; ww < 8; ++ww) Dv += dred[ww][lane];
    const float rD = 1.f / fmaxf(Dv, HS_EPS);

    // ---- pass B: write final att, accumulate sparse y ----
    for (int k0 = 0; k0 < 250; k0 += 5) {
        float e5[5];
        int mm[5];
#pragma unroll
        for (int u = 0; u < 5; ++u) {
            mm[u] = wv + 8 * (k0 + u);
            e5[u] = att[base + ((size_t)mm[u] << 10)];
        }
#pragma unroll
        for (int u = 0; u < 5; ++u) {
            const int m = mm[u];
            float a = e5[u] * rZ;
            float d = a - LAMBDA;
            float s = fmaxf(d, 0.f) * a / (fabsf(d) + HS_EPS);   // bit-identical to pass A
            float v = s * rD;
            att[base + ((size_t)m << 10)] = v;                   // zeros overwrite E too
            unsigned long long msk = __ballot(v != 0.f);
            while (msk) {
                int src = __ffsll(msk) - 1;
                msk &= msk - 1;
                float vv = __shfl(v, src);
                float w0 = W[m * FEA + lane];
                float w1 = W[m * FEA + 64 + lane];
                float w2 = W[m * FEA + 128 + lane];
                float w3 = W[m * FEA + 192 + lane];
                atomicAdd(&ylds[src][lane],       vv * w0);
                atomicAdd(&ylds[src][64 + lane],  vv * w1);
                atomicAdd(&ylds[src][128 + lane], vv * w2);
                atomicAdd(&ylds[src][192 + lane], vv * w3);
            }
        }
    }
    __syncthreads();

    for (int c = wv; c < FEA; c += 8) {
        y[((b * FEA + c) << 10) + hw0 + lane] = ylds[lane][c];
    }
}

// ---------------------------------------------------------------------------
extern "C" void kernel_launch(void* const* d_in, const int* in_sizes, int n_in,
                              void* d_out, int out_size, void* d_ws, size_t ws_size,
                              hipStream_t stream) {
    const float* x = (const float*)d_in[0];
    const float* W = (const float*)d_in[1];
    float* out = (float*)d_out;
    float* y   = out;
    float* att = out + (size_t)Y_ELEMS;
    float* wsf = (float*)d_ws;
    u16*   wsp = (u16*)d_ws;                 // 2 MB
    float* zp  = wsf + WS_ZP;
    u16*   xs  = (u16*)y;                    // 16.8 MB staging in y region
                                             // (consumed before k_pv2 writes y)

    k_split_x    <<<4096, 256, 0, stream>>>(x, xs);
    k_split_w    <<<2048, 256, 0, stream>>>(W, wsp);
    k_scores_mfma<<<2048, 256, 0, stream>>>(xs, wsp, att, zp);
    k_pv2        <<<256, 512, 0, stream>>>(att, W, y, zp);
}

// Round 5
// 188.465 us; speedup vs baseline: 1.2941x; 1.2941x over previous
//
#include <hip/hip_runtime.h>
#include <cfloat>
#include <cmath>

#define MEM_DIM 2000
#define FEA     256
#define LAMBDA  0.0025f
#define HS_EPS  1e-12f

typedef unsigned short u16;
typedef _Float16 f16x8  __attribute__((ext_vector_type(8)));
typedef float    f32x16 __attribute__((ext_vector_type(16)));

static const int Y_ELEMS = 16 * 256 * 1024;   // y output elements

// workspace layout (float offsets): wsp u16[2][2048][256] = 2 MB at 0
#define WS_ZP 524288     // [16][16384] partial sum(e^z) per m-tile (1 MB)
#define WS_DP 786432     // [4][16384]  partial L1(s) per m-slice (0.25 MB)
// xs (f16 split of x, 16.8 MB) lives in the y output region (free until k_pv4).

// ---------------------------------------------------------------------------
// Kernel A: split x [16][256][1024] f32 -> xs planes [2][16][1024][256] f16
// ---------------------------------------------------------------------------
__global__ __launch_bounds__(256) void k_split_x(const float* __restrict__ x,
                                                 u16* __restrict__ xs) {
    __shared__ float tl[32][33];
    const int blk = blockIdx.x;           // 4096 = 16 b * 8 ct * 32 ht
    const int b   = blk >> 8;
    const int ct  = (blk >> 5) & 7;
    const int ht  = blk & 31;
    const int tx  = threadIdx.x & 31, ty = threadIdx.x >> 5;
#pragma unroll
    for (int i = 0; i < 4; ++i)
        tl[ty + 8 * i][tx] =
            x[(((b << 8) + (ct << 5) + ty + (i << 3)) << 10) + (ht << 5) + tx];
    __syncthreads();
#pragma unroll
    for (int i = 0; i < 4; ++i) {
        float v = tl[tx][ty + 8 * i];
        _Float16 a  = (_Float16)v;
        _Float16 bq = (_Float16)((v - (float)a) * 256.0f);
        const int hw = (ht << 5) + ty + (i << 3);
        const int c  = (ct << 5) + tx;
        const size_t o = (((size_t)(b << 10) + hw) << 8) + c;
        xs[o]           = *(u16*)&a;
        xs[4194304 + o] = *(u16*)&bq;
    }
}

// ---------------------------------------------------------------------------
// Kernel B: split W [2000][256] f32 -> wsp [2][2048][256] f16 (m zero-padded)
// ---------------------------------------------------------------------------
__global__ __launch_bounds__(256) void k_split_w(const float* __restrict__ W,
                                                 u16* __restrict__ wsp) {
    const int m = blockIdx.x;             // 2048
    const int c = threadIdx.x;
    float v = (m < MEM_DIM) ? W[(m << 8) + c] : 0.f;
    _Float16 a  = (_Float16)v;
    _Float16 bq = (_Float16)((v - (float)a) * 256.0f);
    wsp[(m << 8) + c]          = *(u16*)&a;
    wsp[524288 + (m << 8) + c] = *(u16*)&bq;
}

// ---------------------------------------------------------------------------
// Kernel 1: z = x.W^T via mfma_f32_32x32x16_f16, 2-split (3 passes, dual acc).
// (unchanged from round 4: 2-phase pipeline, 2-way chunk swizzle)
// ---------------------------------------------------------------------------
__global__ __launch_bounds__(256) void k_scores_mfma(
    const u16* __restrict__ xs, const u16* __restrict__ wsp,
    float* __restrict__ S, float* __restrict__ zp) {
    __shared__ u16 lds[32768];   // 64 KB = 2 x 32 KB buffers
    const int t    = threadIdx.x;
    const int lane = t & 63;
    const int w    = t >> 6;
    const int wr   = w >> 1, wc = w & 1;
    const int lr   = lane & 31, lg = lane >> 5;

    const int bx  = blockIdx.x;
    const int wg  = ((bx & 7) << 8) | (bx >> 3);   // XCD swizzle (2048 = 8*256)
    const int m0t = wg & 15;
    const int rt  = wg >> 4;
    const int m0  = m0t << 7;
    const int b   = rt >> 3;
    const int hw0 = (rt & 7) << 7;

    const u16* gsrc[8];
#pragma unroll
    for (int i = 0; i < 8; ++i) {
        const int s = (i << 8) + t;
        const int tile = s >> 9;
        const int u = s & 511;
        const int r = u >> 2;
        const int cl = (u & 3) ^ ((r >> 1) & 3);
        if (tile < 2)
            gsrc[i] = xs + tile * 4194304 + (((b << 10) + hw0 + r) << 8) + (cl << 3);
        else
            gsrc[i] = wsp + ((tile - 2) << 19) + ((m0 + r) << 8) + (cl << 3);
    }

    f32x16 acc1[2][2], acc2[2][2];
#pragma unroll
    for (int i = 0; i < 2; ++i)
#pragma unroll
        for (int j = 0; j < 2; ++j)
#pragma unroll
            for (int e = 0; e < 16; ++e) { acc1[i][j][e] = 0.f; acc2[i][j][e] = 0.f; }

    #define STAGE(kt, bufb)                                                          \
        {                                                                            \
            _Pragma("unroll")                                                        \
            for (int i = 0; i < 8; ++i) {                                            \
                const int s = (i << 8) + t;                                          \
                __builtin_amdgcn_global_load_lds(                                    \
                    (const __attribute__((address_space(1))) unsigned int*)(gsrc[i] + ((kt) << 5)), \
                    (__attribute__((address_space(3))) unsigned int*)&lds[(bufb) + (s << 3)],       \
                    16, 0, 0);                                                       \
            }                                                                        \
        }

    #define COMPUTE(bufb)                                                            \
        {                                                                            \
            _Pragma("unroll")                                                        \
            for (int ks = 0; ks < 2; ++ks) {                                         \
                f16x8 a0[2], a1[2], b0[2], b1[2];                                    \
                _Pragma("unroll")                                                    \
                for (int ri = 0; ri < 2; ++ri) {                                     \
                    const int R  = (wr << 6) + (ri << 5) + lr;                       \
                    const int pc = ((ks << 1) + lg) ^ ((R >> 1) & 3);                \
                    a0[ri] = *(const f16x8*)&lds[(bufb) +        (R << 5) + (pc << 3)]; \
                    a1[ri] = *(const f16x8*)&lds[(bufb) + 4096 + (R << 5) + (pc << 3)]; \
                }                                                                    \
                _Pragma("unroll")                                                    \
                for (int mi = 0; mi < 2; ++mi) {                                     \
                    const int M  = (wc << 6) + (mi << 5) + lr;                       \
                    const int pc = ((ks << 1) + lg) ^ ((M >> 1) & 3);                \
                    b0[mi] = *(const f16x8*)&lds[(bufb) +  8192 + (M << 5) + (pc << 3)]; \
                    b1[mi] = *(const f16x8*)&lds[(bufb) + 12288 + (M << 5) + (pc << 3)]; \
                }                                                                    \
                _Pragma("unroll")                                                    \
                for (int ri = 0; ri < 2; ++ri)                                       \
                    _Pragma("unroll")                                                \
                    for (int mi = 0; mi < 2; ++mi) {                                 \
                        acc2[ri][mi] = __builtin_amdgcn_mfma_f32_32x32x16_f16(a0[ri], b1[mi], acc2[ri][mi], 0, 0, 0); \
                        acc2[ri][mi] = __builtin_amdgcn_mfma_f32_32x32x16_f16(a1[ri], b0[mi], acc2[ri][mi], 0, 0, 0); \
                        acc1[ri][mi] = __builtin_amdgcn_mfma_f32_32x32x16_f16(a0[ri], b0[mi], acc1[ri][mi], 0, 0, 0); \
                    }                                                                \
            }                                                                        \
        }

    STAGE(0, 0);
    __syncthreads();
#pragma unroll
    for (int kt = 0; kt < 8; ++kt) {
        if (kt < 7) STAGE(kt + 1, ((kt + 1) & 1) << 14);
        COMPUTE((kt & 1) << 14);
        __syncthreads();
    }
    #undef STAGE
    #undef COMPUTE

    float* zf = (float*)lds;

    float rs[2][16];
#pragma unroll
    for (int ri = 0; ri < 2; ++ri)
#pragma unroll
        for (int q = 0; q < 16; ++q) rs[ri][q] = 0.f;

#pragma unroll
    for (int ri = 0; ri < 2; ++ri)
#pragma unroll
        for (int mi = 0; mi < 2; ++mi) {
            const int m = m0 + (wc << 6) + (mi << 5) + lr;
            const bool valid = (m < MEM_DIM);
            float e[16];
#pragma unroll
            for (int q = 0; q < 16; ++q) {
                float z = acc1[ri][mi][q] + acc2[ri][mi][q] * 0.00390625f;
                e[q] = valid ? expf(z) : 0.f;
                rs[ri][q] += e[q];
            }
            if (valid) {
                const size_t pb = ((size_t)(b * MEM_DIM + m) << 10) + hw0
                                + (wr << 6) + (ri << 5) + (lg << 2);
#pragma unroll
                for (int q4 = 0; q4 < 4; ++q4) {
                    float4 v = {e[4 * q4], e[4 * q4 + 1], e[4 * q4 + 2], e[4 * q4 + 3]};
                    *(float4*)&S[pb + (q4 << 3)] = v;
                }
            }
        }

#pragma unroll
    for (int ri = 0; ri < 2; ++ri)
#pragma unroll
        for (int q = 0; q < 16; ++q) {
            float v = rs[ri][q];
            v += __shfl_xor(v, 1);
            v += __shfl_xor(v, 2);
            v += __shfl_xor(v, 4);
            v += __shfl_xor(v, 8);
            v += __shfl_xor(v, 16);
            rs[ri][q] = v;
        }
    if (lr == 0) {
#pragma unroll
        for (int ri = 0; ri < 2; ++ri)
#pragma unroll
            for (int q = 0; q < 16; ++q) {
                const int row = (wr << 6) + (ri << 5) + (q & 3) + ((q >> 2) << 3) + (lg << 2);
                zf[(wc << 7) + row] = rs[ri][q];
            }
    }
    __syncthreads();
    if (t < 128)
        zp[m0t * 16384 + (b << 10) + hw0 + t] = zf[t] + zf[128 + t];
}

// ---------------------------------------------------------------------------
// Kernel 2: D-reduction only (no writes to att). Grid 1024 = 256 row-chunks
// x 4 m-slices of 500; block = 64 rows x 4 m-lanes, fully coalesced reads.
// ---------------------------------------------------------------------------
__global__ __launch_bounds__(256) void k_pvD(const float* __restrict__ att,
                                             const float* __restrict__ zp,
                                             float* __restrict__ dp) {
    __shared__ float red[256];
    const int t    = threadIdx.x;
    const int blk  = blockIdx.x;          // 1024 = 256 chunks x 4 slices
    const int sl   = blk & 3;             // m-slice (500 each)
    const int rc   = blk >> 2;            // row chunk (64 rows)
    const int b    = rc >> 4;
    const int hw0  = (rc & 15) << 6;
    const int lane = t & 63;
    const int mo   = t >> 6;              // 0..3
    const int row  = (b << 10) + hw0 + lane;

    // Z in identical order to k_pv4 -> bit-identical rZ
    float Z = 0.f;
#pragma unroll
    for (int mt = 0; mt < 16; ++mt) Z += zp[mt * 16384 + row];
    const float rZ = 1.f / Z;

    const size_t base = ((size_t)(b * MEM_DIM) << 10) + hw0 + lane;
    float D = 0.f;
    for (int j = 0; j < 125; ++j) {
        const int m = sl * 500 + mo + 4 * j;
        float e = att[base + ((size_t)m << 10)];
        float a = e * rZ;
        float d = a - LAMBDA;
        D += fmaxf(d, 0.f) * a / (fabsf(d) + HS_EPS);
    }
    red[t] = D;
    __syncthreads();
    if (t < 64)
        dp[sl * 16384 + row] = red[t] + red[64 + t] + red[128 + t] + red[192 + t];
}

// ---------------------------------------------------------------------------
// Kernel 3: one pass: read E, recompute s, write final att = s*rD (zeros
// included), ballot-accumulate y into LDS, write y. Block = 16 rows x full m
// (8 waves; wave lane = (m-offset 0..3, row 0..15)). Grid 1024 -> 4 blocks/CU.
// ---------------------------------------------------------------------------
__global__ __launch_bounds__(512) void k_pv4(float* __restrict__ att,
                                             const float* __restrict__ W,
                                             float* __restrict__ y,
                                             const float* __restrict__ zp,
                                             const float* __restrict__ dp) {
    __shared__ float ylds[16][257];
    const int t    = threadIdx.x;
    const int blk  = blockIdx.x;          // 1024 = 16 b x 64 row-chunks(16)
    const int b    = blk >> 6;
    const int hw0  = (blk & 63) << 4;
    const int lane = t & 63, wv = t >> 6;
    const int srow = lane & 15;           // row within chunk
    const int smq  = lane >> 4;           // m offset 0..3
    const int row  = (b << 10) + hw0 + srow;

    for (int i = t; i < 16 * 257; i += 512) ((float*)ylds)[i] = 0.f;

    float Z = 0.f;
#pragma unroll
    for (int mt = 0; mt < 16; ++mt) Z += zp[mt * 16384 + row];
    const float rZ = 1.f / Z;
    float Dv = 0.f;
#pragma unroll
    for (int sl = 0; sl < 4; ++sl) Dv += dp[sl * 16384 + row];
    const float rD = 1.f / fmaxf(Dv, HS_EPS);
    __syncthreads();

    const size_t base = ((size_t)(b * MEM_DIM) << 10) + hw0 + srow;

    // m loop: wave wv covers m = j*32 + wv*4 + smq, j = 0..62 (guard m<2000).
    // 2-deep prefetch breaks the load->ballot serial chain.
    const int m0 = (wv << 2) + smq;
    float e_cur = (m0 < MEM_DIM) ? att[base + ((size_t)m0 << 10)] : 0.f;
    for (int j = 0; j < 63; ++j) {
        const int MB = (j << 5) + (wv << 2);
        const int m  = MB + smq;
        const int mn = MB + 32 + smq;
        float e_nxt = 0.f;
        if (j < 62 && mn < MEM_DIM) e_nxt = att[base + ((size_t)mn << 10)];

        float v = 0.f;
        if (m < MEM_DIM) {
            float a = e_cur * rZ;
            float d = a - LAMBDA;
            float s = fmaxf(d, 0.f) * a / (fabsf(d) + HS_EPS);
            v = s * rD;
            att[base + ((size_t)m << 10)] = v;     // zeros overwrite E too
        }
        unsigned long long msk = __ballot(v != 0.f);
        while (msk) {
            int src = __ffsll(msk) - 1;
            msk &= msk - 1;
            float vv = __shfl(v, src);
            const int ms = MB + (src >> 4);
            const int rs_ = src & 15;
            float w0 = W[ms * FEA + lane];
            float w1 = W[ms * FEA + 64 + lane];
            float w2 = W[ms * FEA + 128 + lane];
            float w3 = W[ms * FEA + 192 + lane];
            float* yp = &ylds[rs_][0];
            atomicAdd(&yp[lane],       vv * w0);
            atomicAdd(&yp[64 + lane],  vv * w1);
            atomicAdd(&yp[128 + lane], vv * w2);
            atomicAdd(&yp[192 + lane], vv * w3);
        }
        e_cur = e_nxt;
    }
    __syncthreads();

    // write y: 16 rows x 256 c
    for (int i = t; i < 4096; i += 512) {
        const int r = i & 15;
        const int c = i >> 4;
        y[(((b << 8) + c) << 10) + hw0 + r] = ylds[r][c];
    }
}

// ---------------------------------------------------------------------------
extern "C" void kernel_launch(void* const* d_in, const int* in_sizes, int n_in,
                              void* d_out, int out_size, void* d_ws, size_t ws_size,
                              hipStream_t stream) {
    const float* x = (const float*)d_in[0];
    const float* W = (const float*)d_in[1];
    float* out = (float*)d_out;
    float* y   = out;
    float* att = out + (size_t)Y_ELEMS;
    float* wsf = (float*)d_ws;
    u16*   wsp = (u16*)d_ws;                 // 2 MB
    float* zp  = wsf + WS_ZP;
    float* dp  = wsf + WS_DP;
    u16*   xs  = (u16*)y;                    // 16.8 MB staging in y region
                                             // (consumed before k_pv4 writes y)

    k_split_x    <<<4096, 256, 0, stream>>>(x, xs);
    k_split_w    <<<2048, 256, 0, stream>>>(W, wsp);
    k_scores_mfma<<<2048, 256, 0, stream>>>(xs, wsp, att, zp);
    k_pvD        <<<1024, 256, 0, stream>>>(att, zp, dp);
    k_pv4        <<<1024, 512, 0, stream>>>(att, W, y, zp, dp);
}